// Round 11
// baseline (369.202 us; speedup 1.0000x reference)
//
#include <hip/hip_runtime.h>
#include <hip/hip_bf16.h>

// GraphEMALayer - MI355X (gfx950) - round 24: passA 8-wide + scalar-stream
// software pipeline.
// R23 post-mortem: 16-wide chunks helped B/C/D (~-10 us, 1-2 accumulators)
// but hurt passA (53.5->59.5 us: 5 accumulators + 16 gather regs pushed
// VGPR 28->36, occupancy 68->59%). Evidence R20-R23: passes are bound by
// the per-chunk s_load->gather serial chain. R24:
//   - passA reverts to 8-wide (proven 53.5 us shape), and
//   - pipelines the scalar stream: chunk i+1's csr/cf s_loads issue
//     BEFORE chunk i's gathers are consumed -> ~200cy scalar latency
//     hides under gather latency. +~16 SGPR, uniform control flow.
// B/C/D stay 16-wide; partition path unchanged. Values identical to R23
// (same accumulation order) -> absmax unchanged. WS 60.0 MB.

static __device__ __forceinline__ float bf2f(unsigned short v) {
    union { unsigned int u; float f; } x;
    x.u = ((unsigned int)v) << 16;
    return x.f;
}

static __device__ __forceinline__ unsigned short f2bf(float f) {
    union { unsigned int u; float f; } x;
    x.f = f;
    unsigned int r = x.u + 0x7FFFu + ((x.u >> 16) & 1u);
    return (unsigned short)(r >> 16);
}

// c from dm1: 0.5*rcp(dm1); exact +0.0f for leaves (dm1==0).
static __device__ __forceinline__ float edge_c(int dm1) {
    float fd = (float)dm1;
    float raw = 0.5f * __builtin_amdgcn_rcpf(fd);
    return (fd == 0.0f) ? 0.0f : raw;
}

// h = x@W + b -> bf16 shadow. Wave = 8 nodes, lane = column.
__global__ void ema_gemm_kernel(const float* __restrict__ x, const float* __restrict__ W,
                                const float* __restrict__ bias, unsigned short* __restrict__ hbf) {
    int wave = (int)((blockIdx.x * 256 + threadIdx.x) >> 6);
    int lane = (int)(threadIdx.x & 63);
    int n0 = wave * 8;
    if (n0 >= 100000) return;
    float w[64];
    #pragma unroll
    for (int k = 0; k < 64; ++k) w[k] = W[k * 64 + lane];   // coalesced, L1-hot
    float bv = bias[lane];
    int nend = (n0 + 8 < 100000) ? (n0 + 8) : 100000;
    for (int n = n0; n < nend; ++n) {
        const float* xr = x + (size_t)__builtin_amdgcn_readfirstlane(n) * 64;
        float acc = bv;
        #pragma unroll
        for (int k = 0; k < 64; ++k) acc = fmaf(xr[k], w[k], acc);
        hbf[n * 64 + lane] = f2bf(acc);
    }
}

// Step 1: per-block bucket histogram. LDS atomics only.
__global__ void ema_hist_kernel(const int* ei, int* hcnt) {
    __shared__ int hist[391];
    int t = (int)threadIdx.x;
    int bl = (int)blockIdx.x;
    for (int i = t; i < 391; i += 256) hist[i] = 0;
    __syncthreads();
    int e0 = bl * 4096;
    #pragma unroll
    for (int i = 0; i < 16; ++i) {
        int e = e0 + t + i * 256;
        if (e < 1600000) {
            int dst = (e < 800000) ? ei[e + 800000] : ei[e - 800000];
            atomicAdd(&hist[dst >> 8], 1);
        }
    }
    __syncthreads();
    for (int i = t; i < 391; i += 256) hcnt[i * 391 + bl] = hist[i];
}

// Step 2a: per-bucket row: exclusive scan of 391 block counts + row total.
__global__ void ema_bscan_row_kernel(int* hcnt, int* btot) {
    __shared__ int s[512];
    int bu = (int)blockIdx.x;
    int t = (int)threadIdx.x;
    int v = (t < 391) ? hcnt[bu * 391 + t] : 0;
    s[t] = v;
    __syncthreads();
    for (int off = 1; off < 512; off <<= 1) {
        int add = (t >= off) ? s[t - off] : 0;
        __syncthreads();
        s[t] += add;
        __syncthreads();
    }
    if (t < 391) hcnt[bu * 391 + t] = s[t] - v;
    if (t == 390) btot[bu] = s[t];
}

// Step 2b: single block: exclusive scan of bucket totals -> bbase[0..391].
__global__ void ema_bscan_base_kernel(const int* btot, int* bbase) {
    __shared__ int s[512];
    int t = (int)threadIdx.x;
    int v = (t < 391) ? btot[t] : 0;
    s[t] = v;
    __syncthreads();
    for (int off = 1; off < 512; off <<= 1) {
        int add = (t >= off) ? s[t - off] : 0;
        __syncthreads();
        s[t] += add;
        __syncthreads();
    }
    if (t < 391) bbase[t] = s[t] - v;
    if (t == 390) bbase[391] = s[t];
}

// Step 3: scatter into stage at per-(bucket,block) bases.
__global__ void ema_scatter_kernel(const int* ei, const int* hcnt,
                                   const int* bbase, unsigned int* stage) {
    __shared__ int base[391];
    __shared__ int cnt[391];
    int t = (int)threadIdx.x;
    int bl = (int)blockIdx.x;
    for (int i = t; i < 391; i += 256) {
        base[i] = hcnt[i * 391 + bl] + bbase[i];
        cnt[i] = 0;
    }
    __syncthreads();
    int e0 = bl * 4096;
    #pragma unroll
    for (int i = 0; i < 16; ++i) {
        int e = e0 + t + i * 256;
        if (e < 1600000) {
            int src = ei[e];
            int dst = (e < 800000) ? ei[e + 800000] : ei[e - 800000];
            int bu = dst >> 8;
            int slot = base[bu] + atomicAdd(&cnt[bu], 1);
            stage[slot] = ((unsigned int)(dst & 255) << 24) | (unsigned int)src;
        }
    }
}

// Step 4 (merged): one block per bucket. Count 256 local ids (LDS), block
// scan -> degi/rs, then re-read the (L2-hot) stage segment and write csr
// (plain src) at per-node slots.
__global__ void ema_fillcsr_kernel(const int* __restrict__ bbase,
                                   const unsigned int* __restrict__ stage,
                                   int* __restrict__ degi,
                                   int* __restrict__ rs,
                                   int* __restrict__ csr) {
    __shared__ int cnt[256];
    __shared__ int scn[256];
    __shared__ int rsl[256];
    int b = (int)blockIdx.x;
    int t = (int)threadIdx.x;
    cnt[t] = 0;
    __syncthreads();
    int seg_lo = bbase[b];
    int seg_hi = bbase[b + 1];
    for (int i = seg_lo + t; i < seg_hi; i += 256) {
        atomicAdd(&cnt[stage[i] >> 24], 1);
    }
    __syncthreads();
    int v = cnt[t];
    scn[t] = v;
    __syncthreads();
    for (int off = 1; off < 256; off <<= 1) {
        int add = (t >= off) ? scn[t - off] : 0;
        __syncthreads();
        scn[t] += add;
        __syncthreads();
    }
    int start = seg_lo + scn[t] - v;
    rsl[t] = start;
    int node = (b << 8) + t;
    if (node < 100000) {
        degi[node] = v;
        rs[node] = start;
    }
    cnt[t] = 0;
    __syncthreads();
    for (int i = seg_lo + t; i < seg_hi; i += 256) {
        unsigned int s = stage[i];
        int local = (int)(s >> 24);
        int srcn = (int)(s & 0x00FFFFFFu);
        int slot = rsl[local] + atomicAdd(&cnt[local], 1);
        csr[slot] = srcn;
    }
}

// cf generation: linear over csr; gather degi[src] (400 KB, L2-resident).
__global__ void ema_cfgen_kernel(const int* __restrict__ csr,
                                 const int* __restrict__ degi,
                                 float* __restrict__ cf) {
    int i = (int)(blockIdx.x * 256 + threadIdx.x);
    if (i >= 1600000) return;
    cf[i] = edge_c(degi[csr[i]] - 1);
}

// cf copy for pass D (cf region of d_out is clobbered by D's writes);
// hbf's slot is dead after pass A.
__global__ void ema_cfcopy_kernel(const float4* __restrict__ cf4,
                                  float4* __restrict__ cfD4) {
    int i = (int)(blockIdx.x * 256 + threadIdx.x);
    if (i < 400000) cfD4[i] = cf4[i];
}

// Pass A: gather hbf rows 8-wide with a pipelined scalar stream (chunk
// i+1's csr/cf s_loads issue before chunk i's gathers are consumed).
__global__ void ema_passA_kernel(const int* __restrict__ degi, const int* __restrict__ rs,
                                 const int* __restrict__ csr, const float* __restrict__ cf,
                                 const unsigned short* __restrict__ hbf,
                                 unsigned short* __restrict__ m0, unsigned short* __restrict__ W1,
                                 unsigned short* __restrict__ W2, unsigned short* __restrict__ W3a,
                                 float2* __restrict__ pp) {
    int wid = (int)((blockIdx.x * 256 + threadIdx.x) >> 6);
    int c = (int)(threadIdx.x & 63);
    if (wid >= 100000) return;
    int dv = __builtin_amdgcn_readfirstlane(degi[wid]);
    int base = wid * 64 + c;
    float hv = bf2f(hbf[base]);
    if (dv == 0) {
        m0[base] = 0;
        W1[base] = 0;
        W2[base] = 0;
        W3a[base] = f2bf(hv);   // y = h for isolated nodes
        if (c == 0) pp[wid] = make_float2(0.0f, 0.0f);
        return;
    }
    int j = __builtin_amdgcn_readfirstlane(rs[wid]);
    int end = j + dv;
    float av = (dv > 1) ? 0.5f : 1.0f;
    float cv = (dv > 1) ? 0.5f / ((float)dv - 1.0f + 1e-9f) : 0.0f;
    float fv = av * hv;
    float sm = 0.0f, sS = 0.0f, sQ = 0.0f, p1 = 0.0f, p2 = 0.0f;
    int A[8];
    float C[8];
    bool have = (j + 8 <= end);
    if (have) {
        #pragma unroll
        for (int u = 0; u < 8; ++u) { A[u] = csr[j + u]; C[u] = cf[j + u]; }
    }
    while (have) {
        int nj = j + 8;
        bool haveN = (nj + 8 <= end);
        int An[8];
        float Cn[8];
        if (haveN) {
            #pragma unroll
            for (int u = 0; u < 8; ++u) { An[u] = csr[nj + u]; Cn[u] = cf[nj + u]; }
        }
        float hh[8];
        #pragma unroll
        for (int u = 0; u < 8; ++u) { hh[u] = bf2f(hbf[A[u] * 64 + c]); }
        #pragma unroll
        for (int u = 0; u < 8; ++u) {
            float al = (C[u] == 0.0f) ? 1.0f : 0.5f;   // scalar cselect
            sm += hh[u];
            sS = fmaf(al, hh[u], sS);
            sQ = fmaf(C[u], hh[u], sQ);
            p1 += C[u];
            p2 = fmaf(C[u], C[u], p2);
        }
        j = nj;
        if (haveN) {
            #pragma unroll
            for (int u = 0; u < 8; ++u) { A[u] = An[u]; C[u] = Cn[u]; }
        }
        have = haveN;
    }
    for (; j < end; ++j) {
        int a = csr[j];
        float ca = cf[j];
        float ha = bf2f(hbf[a * 64 + c]);
        float al = (ca == 0.0f) ? 1.0f : 0.5f;
        sm += ha;
        sS = fmaf(al, ha, sS);
        sQ = fmaf(ca, ha, sQ);
        p1 += ca;
        p2 = fmaf(ca, ca, p2);
    }
    float r = 0.5f / ((float)dv + 1e-9f);
    float w1o = sS - hv * p1;
    float w2o = sS - fv * p1 - cv * p1 * sm + cv * sQ;
    float w3o = 0.5f * hv + r * (sS - fv * p1 + 0.5f * cv * sQ - cv * hv * p2);
    m0[base] = f2bf(sm);
    W1[base] = f2bf(w1o);
    W2[base] = f2bf(w2o);
    W3a[base] = f2bf(w3o);
    if (c == 0) pp[wid] = make_float2(r * cv * p1, r * cv);
}

// Pass B: gather m0 rows 16-wide; m1 = W1 + sum c m0[a];
// W4 = W3a - pp.x*m1 + pp.y*sum c^2 m0[a]. In place over W1/W3a.
__global__ void ema_passB_kernel(const int* __restrict__ degi, const int* __restrict__ rs,
                                 const int* __restrict__ csr, const float* __restrict__ cf,
                                 const unsigned short* __restrict__ m0,
                                 unsigned short* __restrict__ W1m1, unsigned short* __restrict__ W3W4,
                                 const float2* __restrict__ pp) {
    int wid = (int)((blockIdx.x * 256 + threadIdx.x) >> 6);
    int c = (int)(threadIdx.x & 63);
    if (wid >= 100000) return;
    int dv = __builtin_amdgcn_readfirstlane(degi[wid]);
    if (dv == 0) return;   // slots already hold m1=0, W4=h from pass A
    int base = wid * 64 + c;
    int j = __builtin_amdgcn_readfirstlane(rs[wid]);
    int end = j + dv;
    float t1 = 0.0f, t2 = 0.0f;
    for (; j + 16 <= end; j += 16) {
        int aa[16];
        float cc[16];
        float vv[16];
        #pragma unroll
        for (int u = 0; u < 16; ++u) { aa[u] = csr[j + u]; cc[u] = cf[j + u]; }
        #pragma unroll
        for (int u = 0; u < 16; ++u) { vv[u] = bf2f(m0[aa[u] * 64 + c]); }
        #pragma unroll
        for (int u = 0; u < 16; ++u) {
            t1 = fmaf(cc[u], vv[u], t1);
            t2 = fmaf(cc[u] * cc[u], vv[u], t2);
        }
    }
    for (; j + 4 <= end; j += 4) {
        int aa[4];
        float cc[4];
        float vv[4];
        #pragma unroll
        for (int u = 0; u < 4; ++u) { aa[u] = csr[j + u]; cc[u] = cf[j + u]; }
        #pragma unroll
        for (int u = 0; u < 4; ++u) { vv[u] = bf2f(m0[aa[u] * 64 + c]); }
        #pragma unroll
        for (int u = 0; u < 4; ++u) {
            t1 = fmaf(cc[u], vv[u], t1);
            t2 = fmaf(cc[u] * cc[u], vv[u], t2);
        }
    }
    for (; j < end; ++j) {
        float ca = cf[j];
        float mv = bf2f(m0[csr[j] * 64 + c]);
        t1 = fmaf(ca, mv, t1);
        t2 = fmaf(ca * ca, mv, t2);
    }
    float2 ppv = pp[wid];
    float m1 = bf2f(W1m1[base]) + t1;
    float w4 = bf2f(W3W4[base]) - ppv.x * m1 + ppv.y * t2;
    W1m1[base] = f2bf(m1);
    W3W4[base] = f2bf(w4);
}

// Pass C: gather m1 rows 16-wide; m2 = W2 + sum c m1[a] (in place over W2).
__global__ void ema_passC_kernel(const int* __restrict__ degi, const int* __restrict__ rs,
                                 const int* __restrict__ csr, const float* __restrict__ cf,
                                 const unsigned short* __restrict__ m1,
                                 unsigned short* __restrict__ W2m2) {
    int wid = (int)((blockIdx.x * 256 + threadIdx.x) >> 6);
    int c = (int)(threadIdx.x & 63);
    if (wid >= 100000) return;
    int dv = __builtin_amdgcn_readfirstlane(degi[wid]);
    if (dv == 0) return;   // slot already holds m2=0
    int base = wid * 64 + c;
    int j = __builtin_amdgcn_readfirstlane(rs[wid]);
    int end = j + dv;
    float t = 0.0f;
    for (; j + 16 <= end; j += 16) {
        int aa[16];
        float cc[16];
        float vv[16];
        #pragma unroll
        for (int u = 0; u < 16; ++u) { aa[u] = csr[j + u]; cc[u] = cf[j + u]; }
        #pragma unroll
        for (int u = 0; u < 16; ++u) { vv[u] = bf2f(m1[aa[u] * 64 + c]); }
        #pragma unroll
        for (int u = 0; u < 16; ++u) { t = fmaf(cc[u], vv[u], t); }
    }
    for (; j + 4 <= end; j += 4) {
        int aa[4];
        float cc[4];
        float vv[4];
        #pragma unroll
        for (int u = 0; u < 4; ++u) { aa[u] = csr[j + u]; cc[u] = cf[j + u]; }
        #pragma unroll
        for (int u = 0; u < 4; ++u) { vv[u] = bf2f(m1[aa[u] * 64 + c]); }
        #pragma unroll
        for (int u = 0; u < 4; ++u) { t = fmaf(cc[u], vv[u], t); }
    }
    for (; j < end; ++j) {
        t = fmaf(cf[j], bf2f(m1[csr[j] * 64 + c]), t);
    }
    float m2v = bf2f(W2m2[base]) + t;
    W2m2[base] = f2bf(m2v);
}

// Pass D (identifier kernel): gather m2 rows 16-wide; y = W4 + r*sum c m2;
// out = x + relu(y). Reads cfD (copy in dead hbf region).
__global__ void GraphEMALayer_18133351924067_kernel(
    const int* __restrict__ degi, const int* __restrict__ rs,
    const int* __restrict__ csr, const float* __restrict__ cfD,
    const unsigned short* __restrict__ m2, const unsigned short* __restrict__ W4,
    const float* __restrict__ x, float* __restrict__ out) {
    int wid = (int)((blockIdx.x * 256 + threadIdx.x) >> 6);
    int c = (int)(threadIdx.x & 63);
    if (wid >= 100000) return;
    int dv = __builtin_amdgcn_readfirstlane(degi[wid]);
    int base = wid * 64 + c;
    float xv = x[base];
    float y = bf2f(W4[base]);
    if (dv > 0) {
        int j = __builtin_amdgcn_readfirstlane(rs[wid]);
        int end = j + dv;
        float t = 0.0f;
        for (; j + 16 <= end; j += 16) {
            int aa[16];
            float cc[16];
            float vv[16];
            #pragma unroll
            for (int u = 0; u < 16; ++u) { aa[u] = csr[j + u]; cc[u] = cfD[j + u]; }
            #pragma unroll
            for (int u = 0; u < 16; ++u) { vv[u] = bf2f(m2[aa[u] * 64 + c]); }
            #pragma unroll
            for (int u = 0; u < 16; ++u) { t = fmaf(cc[u], vv[u], t); }
        }
        for (; j + 4 <= end; j += 4) {
            int aa[4];
            float cc[4];
            float vv[4];
            #pragma unroll
            for (int u = 0; u < 4; ++u) { aa[u] = csr[j + u]; cc[u] = cfD[j + u]; }
            #pragma unroll
            for (int u = 0; u < 4; ++u) { vv[u] = bf2f(m2[aa[u] * 64 + c]); }
            #pragma unroll
            for (int u = 0; u < 4; ++u) { t = fmaf(cc[u], vv[u], t); }
        }
        for (; j < end; ++j) {
            t = fmaf(cfD[j], bf2f(m2[csr[j] * 64 + c]), t);
        }
        float r = 0.5f / ((float)dv + 1e-9f);
        y += r * t;
    }
    if (y < 0.0f) y = 0.0f;
    out[base] = xv + y;
}

extern "C" void kernel_launch(void* const* d_in, const int* in_sizes, int n_in,
                              void* d_out, int out_size, void* d_ws, size_t ws_size,
                              hipStream_t stream) {
    (void)in_sizes; (void)n_in; (void)out_size; (void)ws_size;

    const float* x    = (const float*)d_in[0];
    const int*   ei   = (const int*)d_in[1];
    const float* W    = (const float*)d_in[2];
    const float* bias = (const float*)d_in[3];
    float* out = (float*)d_out;
    unsigned short* m0 = (unsigned short*)d_out;    // [0, 12.8M): dead before D
    float* cf  = (float*)((char*)d_out + 12800000); // [12.8, 19.2M): dead before D

    char* ws = (char*)d_ws;
    unsigned short* hbf  = (unsigned short*)(ws);             // 12,800,000 B
    unsigned short* W1m1 = (unsigned short*)(ws + 12800000);  // 12,800,000 B
    unsigned short* W2m2 = (unsigned short*)(ws + 25600000);  // 12,800,000 B
    unsigned short* W3W4 = (unsigned short*)(ws + 38400000);  // 12,800,000 B
    int* degi = (int*)(ws + 51200000);                        //    400,000 B
    int* rs   = (int*)(ws + 51600000);                        //    400,000 B
    float2* pp  = (float2*)(ws + 52800000);                   //    800,000 B
    int* csr  = (int*)(ws + 53600000);                        //  6,400,000 B
    int* bbase = (int*)(ws + 60000000);                       //      1,568 B
    int* btot  = (int*)(ws + 60002048);                       //      1,564 B

    // CSR-build scratch, dead before pass A writes the aliased regions:
    unsigned int* stage = (unsigned int*)(ws + 12800000);     // aliases W1m1, 6.4 MB
    int* hcnt = (int*)(ws + 25600000);                        // aliases W2m2, 611,524 B
    float* cfD = (float*)(ws);                                // aliases hbf (dead after A)

    int eb = (100000 * 64 + 255) / 256;   // 25000 blocks: wave-per-node grids
    int nb = (100000 + 255) / 256;        //   391 blocks: per-bucket grids
    int pb = (1600000 + 4095) / 4096;     //   391 blocks: partition grids
    int gb = (100000 + 31) / 32;          //  3125 blocks: gemm (32 nodes/block)
    int db = (1600000 + 255) / 256;       //  6250 blocks: cfgen
    int cb = (400000 + 255) / 256;        //  1563 blocks: cf copy (float4)

    ema_gemm_kernel<<<gb, 256, 0, stream>>>(x, W, bias, hbf);

    ema_hist_kernel<<<pb, 256, 0, stream>>>(ei, hcnt);
    ema_bscan_row_kernel<<<391, 512, 0, stream>>>(hcnt, btot);
    ema_bscan_base_kernel<<<1, 512, 0, stream>>>(btot, bbase);
    ema_scatter_kernel<<<pb, 256, 0, stream>>>(ei, hcnt, bbase, stage);
    ema_fillcsr_kernel<<<nb, 256, 0, stream>>>(bbase, stage, degi, rs, csr);
    ema_cfgen_kernel<<<db, 256, 0, stream>>>(csr, degi, cf);

    ema_passA_kernel<<<eb, 256, 0, stream>>>(degi, rs, csr, cf, hbf,
                                             m0, W1m1, W2m2, W3W4, pp);
    ema_cfcopy_kernel<<<cb, 256, 0, stream>>>((const float4*)cf, (float4*)cfD);
    ema_passB_kernel<<<eb, 256, 0, stream>>>(degi, rs, csr, cf, m0,
                                             W1m1, W3W4, pp);
    ema_passC_kernel<<<eb, 256, 0, stream>>>(degi, rs, csr, cf, W1m1, W2m2);
    GraphEMALayer_18133351924067_kernel<<<eb, 256, 0, stream>>>(
        degi, rs, csr, cfD, W2m2, W3W4, x, out);
}

// Round 12
// 353.716 us; speedup vs baseline: 1.0438x; 1.0438x over previous
//
#include <hip/hip_runtime.h>
#include <hip/hip_bf16.h>

// GraphEMALayer - MI355X (gfx950) - round 25: best-known recombination.
// R24 post-mortem: explicit scalar-stream pipeline REGRESSED passA
// (59.5->66.4 us; SGPR 96, occ 60%) -- the rotation copies serialized
// what the compiler already overlapped. passA scoreboard: 8-wide simple
// 53.5 (R20) / 16-wide 59.5 (R23) / pipelined 66.4 (R24). B/C/D 16-wide
// is a proven win (R23). R25 = R23 with passA reverted to the plain
// 8-wide R20 loop: 5 accumulators -> 8-wide register sweet spot;
// B/C/D (1-2 accumulators) stay 16-wide. No new mechanisms.
// Values identical to the respective best-measured kernels. WS 60.0 MB.

static __device__ __forceinline__ float bf2f(unsigned short v) {
    union { unsigned int u; float f; } x;
    x.u = ((unsigned int)v) << 16;
    return x.f;
}

static __device__ __forceinline__ unsigned short f2bf(float f) {
    union { unsigned int u; float f; } x;
    x.f = f;
    unsigned int r = x.u + 0x7FFFu + ((x.u >> 16) & 1u);
    return (unsigned short)(r >> 16);
}

// c from dm1: 0.5*rcp(dm1); exact +0.0f for leaves (dm1==0).
static __device__ __forceinline__ float edge_c(int dm1) {
    float fd = (float)dm1;
    float raw = 0.5f * __builtin_amdgcn_rcpf(fd);
    return (fd == 0.0f) ? 0.0f : raw;
}

// h = x@W + b -> bf16 shadow. Wave = 8 nodes, lane = column.
__global__ void ema_gemm_kernel(const float* __restrict__ x, const float* __restrict__ W,
                                const float* __restrict__ bias, unsigned short* __restrict__ hbf) {
    int wave = (int)((blockIdx.x * 256 + threadIdx.x) >> 6);
    int lane = (int)(threadIdx.x & 63);
    int n0 = wave * 8;
    if (n0 >= 100000) return;
    float w[64];
    #pragma unroll
    for (int k = 0; k < 64; ++k) w[k] = W[k * 64 + lane];   // coalesced, L1-hot
    float bv = bias[lane];
    int nend = (n0 + 8 < 100000) ? (n0 + 8) : 100000;
    for (int n = n0; n < nend; ++n) {
        const float* xr = x + (size_t)__builtin_amdgcn_readfirstlane(n) * 64;
        float acc = bv;
        #pragma unroll
        for (int k = 0; k < 64; ++k) acc = fmaf(xr[k], w[k], acc);
        hbf[n * 64 + lane] = f2bf(acc);
    }
}

// Step 1: per-block bucket histogram. LDS atomics only.
__global__ void ema_hist_kernel(const int* ei, int* hcnt) {
    __shared__ int hist[391];
    int t = (int)threadIdx.x;
    int bl = (int)blockIdx.x;
    for (int i = t; i < 391; i += 256) hist[i] = 0;
    __syncthreads();
    int e0 = bl * 4096;
    #pragma unroll
    for (int i = 0; i < 16; ++i) {
        int e = e0 + t + i * 256;
        if (e < 1600000) {
            int dst = (e < 800000) ? ei[e + 800000] : ei[e - 800000];
            atomicAdd(&hist[dst >> 8], 1);
        }
    }
    __syncthreads();
    for (int i = t; i < 391; i += 256) hcnt[i * 391 + bl] = hist[i];
}

// Step 2a: per-bucket row: exclusive scan of 391 block counts + row total.
__global__ void ema_bscan_row_kernel(int* hcnt, int* btot) {
    __shared__ int s[512];
    int bu = (int)blockIdx.x;
    int t = (int)threadIdx.x;
    int v = (t < 391) ? hcnt[bu * 391 + t] : 0;
    s[t] = v;
    __syncthreads();
    for (int off = 1; off < 512; off <<= 1) {
        int add = (t >= off) ? s[t - off] : 0;
        __syncthreads();
        s[t] += add;
        __syncthreads();
    }
    if (t < 391) hcnt[bu * 391 + t] = s[t] - v;
    if (t == 390) btot[bu] = s[t];
}

// Step 2b: single block: exclusive scan of bucket totals -> bbase[0..391].
__global__ void ema_bscan_base_kernel(const int* btot, int* bbase) {
    __shared__ int s[512];
    int t = (int)threadIdx.x;
    int v = (t < 391) ? btot[t] : 0;
    s[t] = v;
    __syncthreads();
    for (int off = 1; off < 512; off <<= 1) {
        int add = (t >= off) ? s[t - off] : 0;
        __syncthreads();
        s[t] += add;
        __syncthreads();
    }
    if (t < 391) bbase[t] = s[t] - v;
    if (t == 390) bbase[391] = s[t];
}

// Step 3: scatter into stage at per-(bucket,block) bases.
__global__ void ema_scatter_kernel(const int* ei, const int* hcnt,
                                   const int* bbase, unsigned int* stage) {
    __shared__ int base[391];
    __shared__ int cnt[391];
    int t = (int)threadIdx.x;
    int bl = (int)blockIdx.x;
    for (int i = t; i < 391; i += 256) {
        base[i] = hcnt[i * 391 + bl] + bbase[i];
        cnt[i] = 0;
    }
    __syncthreads();
    int e0 = bl * 4096;
    #pragma unroll
    for (int i = 0; i < 16; ++i) {
        int e = e0 + t + i * 256;
        if (e < 1600000) {
            int src = ei[e];
            int dst = (e < 800000) ? ei[e + 800000] : ei[e - 800000];
            int bu = dst >> 8;
            int slot = base[bu] + atomicAdd(&cnt[bu], 1);
            stage[slot] = ((unsigned int)(dst & 255) << 24) | (unsigned int)src;
        }
    }
}

// Step 4 (merged): one block per bucket. Count 256 local ids (LDS), block
// scan -> degi/rs, then re-read the (L2-hot) stage segment and write csr
// (plain src) at per-node slots.
__global__ void ema_fillcsr_kernel(const int* __restrict__ bbase,
                                   const unsigned int* __restrict__ stage,
                                   int* __restrict__ degi,
                                   int* __restrict__ rs,
                                   int* __restrict__ csr) {
    __shared__ int cnt[256];
    __shared__ int scn[256];
    __shared__ int rsl[256];
    int b = (int)blockIdx.x;
    int t = (int)threadIdx.x;
    cnt[t] = 0;
    __syncthreads();
    int seg_lo = bbase[b];
    int seg_hi = bbase[b + 1];
    for (int i = seg_lo + t; i < seg_hi; i += 256) {
        atomicAdd(&cnt[stage[i] >> 24], 1);
    }
    __syncthreads();
    int v = cnt[t];
    scn[t] = v;
    __syncthreads();
    for (int off = 1; off < 256; off <<= 1) {
        int add = (t >= off) ? scn[t - off] : 0;
        __syncthreads();
        scn[t] += add;
        __syncthreads();
    }
    int start = seg_lo + scn[t] - v;
    rsl[t] = start;
    int node = (b << 8) + t;
    if (node < 100000) {
        degi[node] = v;
        rs[node] = start;
    }
    cnt[t] = 0;
    __syncthreads();
    for (int i = seg_lo + t; i < seg_hi; i += 256) {
        unsigned int s = stage[i];
        int local = (int)(s >> 24);
        int srcn = (int)(s & 0x00FFFFFFu);
        int slot = rsl[local] + atomicAdd(&cnt[local], 1);
        csr[slot] = srcn;
    }
}

// cf generation: linear over csr; gather degi[src] (400 KB, L2-resident).
__global__ void ema_cfgen_kernel(const int* __restrict__ csr,
                                 const int* __restrict__ degi,
                                 float* __restrict__ cf) {
    int i = (int)(blockIdx.x * 256 + threadIdx.x);
    if (i >= 1600000) return;
    cf[i] = edge_c(degi[csr[i]] - 1);
}

// cf copy for pass D (cf region of d_out is clobbered by D's writes);
// hbf's slot is dead after pass A.
__global__ void ema_cfcopy_kernel(const float4* __restrict__ cf4,
                                  float4* __restrict__ cfD4) {
    int i = (int)(blockIdx.x * 256 + threadIdx.x);
    if (i < 400000) cfD4[i] = cf4[i];
}

// Pass A: gather hbf rows 8-wide (R20 proven shape); emit m0,W1,W2,W3a,pp.
__global__ void ema_passA_kernel(const int* __restrict__ degi, const int* __restrict__ rs,
                                 const int* __restrict__ csr, const float* __restrict__ cf,
                                 const unsigned short* __restrict__ hbf,
                                 unsigned short* __restrict__ m0, unsigned short* __restrict__ W1,
                                 unsigned short* __restrict__ W2, unsigned short* __restrict__ W3a,
                                 float2* __restrict__ pp) {
    int wid = (int)((blockIdx.x * 256 + threadIdx.x) >> 6);
    int c = (int)(threadIdx.x & 63);
    if (wid >= 100000) return;
    int dv = __builtin_amdgcn_readfirstlane(degi[wid]);
    int base = wid * 64 + c;
    float hv = bf2f(hbf[base]);
    if (dv == 0) {
        m0[base] = 0;
        W1[base] = 0;
        W2[base] = 0;
        W3a[base] = f2bf(hv);   // y = h for isolated nodes
        if (c == 0) pp[wid] = make_float2(0.0f, 0.0f);
        return;
    }
    int j = __builtin_amdgcn_readfirstlane(rs[wid]);
    int end = j + dv;
    float av = (dv > 1) ? 0.5f : 1.0f;
    float cv = (dv > 1) ? 0.5f / ((float)dv - 1.0f + 1e-9f) : 0.0f;
    float fv = av * hv;
    float sm = 0.0f, sS = 0.0f, sQ = 0.0f, p1 = 0.0f, p2 = 0.0f;
    for (; j + 8 <= end; j += 8) {
        int a0 = csr[j],     a1 = csr[j + 1], a2 = csr[j + 2], a3 = csr[j + 3];
        int a4 = csr[j + 4], a5 = csr[j + 5], a6 = csr[j + 6], a7 = csr[j + 7];
        float c0 = cf[j],     c1 = cf[j + 1], c2 = cf[j + 2], c3 = cf[j + 3];
        float c4 = cf[j + 4], c5 = cf[j + 5], c6 = cf[j + 6], c7 = cf[j + 7];
        float h0 = bf2f(hbf[a0 * 64 + c]);
        float h1 = bf2f(hbf[a1 * 64 + c]);
        float h2 = bf2f(hbf[a2 * 64 + c]);
        float h3 = bf2f(hbf[a3 * 64 + c]);
        float h4 = bf2f(hbf[a4 * 64 + c]);
        float h5 = bf2f(hbf[a5 * 64 + c]);
        float h6 = bf2f(hbf[a6 * 64 + c]);
        float h7 = bf2f(hbf[a7 * 64 + c]);
        float al0 = (c0 == 0.0f) ? 1.0f : 0.5f;   // scalar cselect
        float al1 = (c1 == 0.0f) ? 1.0f : 0.5f;
        float al2 = (c2 == 0.0f) ? 1.0f : 0.5f;
        float al3 = (c3 == 0.0f) ? 1.0f : 0.5f;
        float al4 = (c4 == 0.0f) ? 1.0f : 0.5f;
        float al5 = (c5 == 0.0f) ? 1.0f : 0.5f;
        float al6 = (c6 == 0.0f) ? 1.0f : 0.5f;
        float al7 = (c7 == 0.0f) ? 1.0f : 0.5f;
        sm += ((h0 + h1) + (h2 + h3)) + ((h4 + h5) + (h6 + h7));
        sS += (al0 * h0 + al1 * h1 + al2 * h2 + al3 * h3)
            + (al4 * h4 + al5 * h5 + al6 * h6 + al7 * h7);
        sQ += (c0 * h0 + c1 * h1 + c2 * h2 + c3 * h3)
            + (c4 * h4 + c5 * h5 + c6 * h6 + c7 * h7);
        p1 += ((c0 + c1) + (c2 + c3)) + ((c4 + c5) + (c6 + c7));
        p2 += (c0 * c0 + c1 * c1 + c2 * c2 + c3 * c3)
            + (c4 * c4 + c5 * c5 + c6 * c6 + c7 * c7);
    }
    for (; j + 4 <= end; j += 4) {
        int a0 = csr[j], a1 = csr[j + 1], a2 = csr[j + 2], a3 = csr[j + 3];
        float c0 = cf[j], c1 = cf[j + 1], c2 = cf[j + 2], c3 = cf[j + 3];
        float h0 = bf2f(hbf[a0 * 64 + c]);
        float h1 = bf2f(hbf[a1 * 64 + c]);
        float h2 = bf2f(hbf[a2 * 64 + c]);
        float h3 = bf2f(hbf[a3 * 64 + c]);
        float al0 = (c0 == 0.0f) ? 1.0f : 0.5f;
        float al1 = (c1 == 0.0f) ? 1.0f : 0.5f;
        float al2 = (c2 == 0.0f) ? 1.0f : 0.5f;
        float al3 = (c3 == 0.0f) ? 1.0f : 0.5f;
        sm += (h0 + h1) + (h2 + h3);
        sS += al0 * h0 + al1 * h1 + al2 * h2 + al3 * h3;
        sQ += c0 * h0 + c1 * h1 + c2 * h2 + c3 * h3;
        p1 += (c0 + c1) + (c2 + c3);
        p2 += c0 * c0 + c1 * c1 + c2 * c2 + c3 * c3;
    }
    for (; j < end; ++j) {
        int a = csr[j];
        float ca = cf[j];
        float ha = bf2f(hbf[a * 64 + c]);
        float al = (ca == 0.0f) ? 1.0f : 0.5f;
        sm += ha;
        sS = fmaf(al, ha, sS);
        sQ = fmaf(ca, ha, sQ);
        p1 += ca;
        p2 = fmaf(ca, ca, p2);
    }
    float r = 0.5f / ((float)dv + 1e-9f);
    float w1o = sS - hv * p1;
    float w2o = sS - fv * p1 - cv * p1 * sm + cv * sQ;
    float w3o = 0.5f * hv + r * (sS - fv * p1 + 0.5f * cv * sQ - cv * hv * p2);
    m0[base] = f2bf(sm);
    W1[base] = f2bf(w1o);
    W2[base] = f2bf(w2o);
    W3a[base] = f2bf(w3o);
    if (c == 0) pp[wid] = make_float2(r * cv * p1, r * cv);
}

// Pass B: gather m0 rows 16-wide; m1 = W1 + sum c m0[a];
// W4 = W3a - pp.x*m1 + pp.y*sum c^2 m0[a]. In place over W1/W3a.
__global__ void ema_passB_kernel(const int* __restrict__ degi, const int* __restrict__ rs,
                                 const int* __restrict__ csr, const float* __restrict__ cf,
                                 const unsigned short* __restrict__ m0,
                                 unsigned short* __restrict__ W1m1, unsigned short* __restrict__ W3W4,
                                 const float2* __restrict__ pp) {
    int wid = (int)((blockIdx.x * 256 + threadIdx.x) >> 6);
    int c = (int)(threadIdx.x & 63);
    if (wid >= 100000) return;
    int dv = __builtin_amdgcn_readfirstlane(degi[wid]);
    if (dv == 0) return;   // slots already hold m1=0, W4=h from pass A
    int base = wid * 64 + c;
    int j = __builtin_amdgcn_readfirstlane(rs[wid]);
    int end = j + dv;
    float t1 = 0.0f, t2 = 0.0f;
    for (; j + 16 <= end; j += 16) {
        int aa[16];
        float cc[16];
        float vv[16];
        #pragma unroll
        for (int u = 0; u < 16; ++u) { aa[u] = csr[j + u]; cc[u] = cf[j + u]; }
        #pragma unroll
        for (int u = 0; u < 16; ++u) { vv[u] = bf2f(m0[aa[u] * 64 + c]); }
        #pragma unroll
        for (int u = 0; u < 16; ++u) {
            t1 = fmaf(cc[u], vv[u], t1);
            t2 = fmaf(cc[u] * cc[u], vv[u], t2);
        }
    }
    for (; j + 4 <= end; j += 4) {
        int aa[4];
        float cc[4];
        float vv[4];
        #pragma unroll
        for (int u = 0; u < 4; ++u) { aa[u] = csr[j + u]; cc[u] = cf[j + u]; }
        #pragma unroll
        for (int u = 0; u < 4; ++u) { vv[u] = bf2f(m0[aa[u] * 64 + c]); }
        #pragma unroll
        for (int u = 0; u < 4; ++u) {
            t1 = fmaf(cc[u], vv[u], t1);
            t2 = fmaf(cc[u] * cc[u], vv[u], t2);
        }
    }
    for (; j < end; ++j) {
        float ca = cf[j];
        float mv = bf2f(m0[csr[j] * 64 + c]);
        t1 = fmaf(ca, mv, t1);
        t2 = fmaf(ca * ca, mv, t2);
    }
    float2 ppv = pp[wid];
    float m1 = bf2f(W1m1[base]) + t1;
    float w4 = bf2f(W3W4[base]) - ppv.x * m1 + ppv.y * t2;
    W1m1[base] = f2bf(m1);
    W3W4[base] = f2bf(w4);
}

// Pass C: gather m1 rows 16-wide; m2 = W2 + sum c m1[a] (in place over W2).
__global__ void ema_passC_kernel(const int* __restrict__ degi, const int* __restrict__ rs,
                                 const int* __restrict__ csr, const float* __restrict__ cf,
                                 const unsigned short* __restrict__ m1,
                                 unsigned short* __restrict__ W2m2) {
    int wid = (int)((blockIdx.x * 256 + threadIdx.x) >> 6);
    int c = (int)(threadIdx.x & 63);
    if (wid >= 100000) return;
    int dv = __builtin_amdgcn_readfirstlane(degi[wid]);
    if (dv == 0) return;   // slot already holds m2=0
    int base = wid * 64 + c;
    int j = __builtin_amdgcn_readfirstlane(rs[wid]);
    int end = j + dv;
    float t = 0.0f;
    for (; j + 16 <= end; j += 16) {
        int aa[16];
        float cc[16];
        float vv[16];
        #pragma unroll
        for (int u = 0; u < 16; ++u) { aa[u] = csr[j + u]; cc[u] = cf[j + u]; }
        #pragma unroll
        for (int u = 0; u < 16; ++u) { vv[u] = bf2f(m1[aa[u] * 64 + c]); }
        #pragma unroll
        for (int u = 0; u < 16; ++u) { t = fmaf(cc[u], vv[u], t); }
    }
    for (; j + 4 <= end; j += 4) {
        int aa[4];
        float cc[4];
        float vv[4];
        #pragma unroll
        for (int u = 0; u < 4; ++u) { aa[u] = csr[j + u]; cc[u] = cf[j + u]; }
        #pragma unroll
        for (int u = 0; u < 4; ++u) { vv[u] = bf2f(m1[aa[u] * 64 + c]); }
        #pragma unroll
        for (int u = 0; u < 4; ++u) { t = fmaf(cc[u], vv[u], t); }
    }
    for (; j < end; ++j) {
        t = fmaf(cf[j], bf2f(m1[csr[j] * 64 + c]), t);
    }
    float m2v = bf2f(W2m2[base]) + t;
    W2m2[base] = f2bf(m2v);
}

// Pass D (identifier kernel): gather m2 rows 16-wide; y = W4 + r*sum c m2;
// out = x + relu(y). Reads cfD (copy in dead hbf region).
__global__ void GraphEMALayer_18133351924067_kernel(
    const int* __restrict__ degi, const int* __restrict__ rs,
    const int* __restrict__ csr, const float* __restrict__ cfD,
    const unsigned short* __restrict__ m2, const unsigned short* __restrict__ W4,
    const float* __restrict__ x, float* __restrict__ out) {
    int wid = (int)((blockIdx.x * 256 + threadIdx.x) >> 6);
    int c = (int)(threadIdx.x & 63);
    if (wid >= 100000) return;
    int dv = __builtin_amdgcn_readfirstlane(degi[wid]);
    int base = wid * 64 + c;
    float xv = x[base];
    float y = bf2f(W4[base]);
    if (dv > 0) {
        int j = __builtin_amdgcn_readfirstlane(rs[wid]);
        int end = j + dv;
        float t = 0.0f;
        for (; j + 16 <= end; j += 16) {
            int aa[16];
            float cc[16];
            float vv[16];
            #pragma unroll
            for (int u = 0; u < 16; ++u) { aa[u] = csr[j + u]; cc[u] = cfD[j + u]; }
            #pragma unroll
            for (int u = 0; u < 16; ++u) { vv[u] = bf2f(m2[aa[u] * 64 + c]); }
            #pragma unroll
            for (int u = 0; u < 16; ++u) { t = fmaf(cc[u], vv[u], t); }
        }
        for (; j + 4 <= end; j += 4) {
            int aa[4];
            float cc[4];
            float vv[4];
            #pragma unroll
            for (int u = 0; u < 4; ++u) { aa[u] = csr[j + u]; cc[u] = cfD[j + u]; }
            #pragma unroll
            for (int u = 0; u < 4; ++u) { vv[u] = bf2f(m2[aa[u] * 64 + c]); }
            #pragma unroll
            for (int u = 0; u < 4; ++u) { t = fmaf(cc[u], vv[u], t); }
        }
        for (; j < end; ++j) {
            t = fmaf(cfD[j], bf2f(m2[csr[j] * 64 + c]), t);
        }
        float r = 0.5f / ((float)dv + 1e-9f);
        y += r * t;
    }
    if (y < 0.0f) y = 0.0f;
    out[base] = xv + y;
}

extern "C" void kernel_launch(void* const* d_in, const int* in_sizes, int n_in,
                              void* d_out, int out_size, void* d_ws, size_t ws_size,
                              hipStream_t stream) {
    (void)in_sizes; (void)n_in; (void)out_size; (void)ws_size;

    const float* x    = (const float*)d_in[0];
    const int*   ei   = (const int*)d_in[1];
    const float* W    = (const float*)d_in[2];
    const float* bias = (const float*)d_in[3];
    float* out = (float*)d_out;
    unsigned short* m0 = (unsigned short*)d_out;    // [0, 12.8M): dead before D
    float* cf  = (float*)((char*)d_out + 12800000); // [12.8, 19.2M): dead before D

    char* ws = (char*)d_ws;
    unsigned short* hbf  = (unsigned short*)(ws);             // 12,800,000 B
    unsigned short* W1m1 = (unsigned short*)(ws + 12800000);  // 12,800,000 B
    unsigned short* W2m2 = (unsigned short*)(ws + 25600000);  // 12,800,000 B
    unsigned short* W3W4 = (unsigned short*)(ws + 38400000);  // 12,800,000 B
    int* degi = (int*)(ws + 51200000);                        //    400,000 B
    int* rs   = (int*)(ws + 51600000);                        //    400,000 B
    float2* pp  = (float2*)(ws + 52800000);                   //    800,000 B
    int* csr  = (int*)(ws + 53600000);                        //  6,400,000 B
    int* bbase = (int*)(ws + 60000000);                       //      1,568 B
    int* btot  = (int*)(ws + 60002048);                       //      1,564 B

    // CSR-build scratch, dead before pass A writes the aliased regions:
    unsigned int* stage = (unsigned int*)(ws + 12800000);     // aliases W1m1, 6.4 MB
    int* hcnt = (int*)(ws + 25600000);                        // aliases W2m2, 611,524 B
    float* cfD = (float*)(ws);                                // aliases hbf (dead after A)

    int eb = (100000 * 64 + 255) / 256;   // 25000 blocks: wave-per-node grids
    int nb = (100000 + 255) / 256;        //   391 blocks: per-bucket grids
    int pb = (1600000 + 4095) / 4096;     //   391 blocks: partition grids
    int gb = (100000 + 31) / 32;          //  3125 blocks: gemm (32 nodes/block)
    int db = (1600000 + 255) / 256;       //  6250 blocks: cfgen
    int cb = (400000 + 255) / 256;        //  1563 blocks: cf copy (float4)

    ema_gemm_kernel<<<gb, 256, 0, stream>>>(x, W, bias, hbf);

    ema_hist_kernel<<<pb, 256, 0, stream>>>(ei, hcnt);
    ema_bscan_row_kernel<<<391, 512, 0, stream>>>(hcnt, btot);
    ema_bscan_base_kernel<<<1, 512, 0, stream>>>(btot, bbase);
    ema_scatter_kernel<<<pb, 256, 0, stream>>>(ei, hcnt, bbase, stage);
    ema_fillcsr_kernel<<<nb, 256, 0, stream>>>(bbase, stage, degi, rs, csr);
    ema_cfgen_kernel<<<db, 256, 0, stream>>>(csr, degi, cf);

    ema_passA_kernel<<<eb, 256, 0, stream>>>(degi, rs, csr, cf, hbf,
                                             m0, W1m1, W2m2, W3W4, pp);
    ema_cfcopy_kernel<<<cb, 256, 0, stream>>>((const float4*)cf, (float4*)cfD);
    ema_passB_kernel<<<eb, 256, 0, stream>>>(degi, rs, csr, cf, m0,
                                             W1m1, W3W4, pp);
    ema_passC_kernel<<<eb, 256, 0, stream>>>(degi, rs, csr, cf, W1m1, W2m2);
    GraphEMALayer_18133351924067_kernel<<<eb, 256, 0, stream>>>(
        degi, rs, csr, cfD, W2m2, W3W4, x, out);
}